// Round 1
// baseline (125.841 us; speedup 1.0000x reference)
//
#include <hip/hip_runtime.h>

#define TT 48
#define II 5
#define HID 8

// quad_perm DPP move: returns v from lane (quad_base | perm[lane&3])
template<int CTRL>
__device__ __forceinline__ float dppf(float v) {
    return __int_as_float(__builtin_amdgcn_update_dpp(0, __float_as_int(v), CTRL, 0xF, 0xF, true));
}
// xor1 = quad_perm[1,0,3,2] = 0xB1 ; xor2 = [2,3,0,1] = 0x4E ; xor3 = [3,2,1,0] = 0x1B

__device__ __forceinline__ float fast_sigmoid(float x) {
    return __builtin_amdgcn_rcpf(1.0f + __expf(-x));
}
__device__ __forceinline__ float fast_tanh(float x) {
    // 1 - 2/(1+exp(2x)); saturates correctly at +/-1 for large |x|
    return fmaf(-2.0f, __builtin_amdgcn_rcpf(1.0f + __expf(2.0f * x)), 1.0f);
}

__global__ __launch_bounds__(256) void lstm_fused(
    const float* __restrict__ x,
    const float* __restrict__ W_ih,
    const float* __restrict__ W_hh,
    const float* __restrict__ b_ih,
    const float* __restrict__ b_hh,
    const float* __restrict__ fc_W,
    const float* __restrict__ fc_b,
    float* __restrict__ out, int B)
{
    __shared__ __align__(16) float s_fc[TT * HID];
    const int tid = threadIdx.x;
    for (int i = tid; i < TT * HID; i += 256) s_fc[i] = fc_W[i];
    __syncthreads();

    const int b = blockIdx.x * 64 + (tid >> 2);
    const int q = tid & 3;
    if (b >= B) return;

    // gather position m=0..7 holds h-element e(m) = 2*(q ^ (m>>1)) + (m&1)
    int eidx[8];
    #pragma unroll
    for (int m = 0; m < 8; ++m) eidx[m] = 2 * (q ^ (m >> 1)) + (m & 1);

    // this thread owns hidden elements 2q, 2q+1 -> gate rows gi*8 + 2q + s
    // local row index r = gi*2 + s  (gi: 0=i, 1=f, 2=g, 3=o)
    float wih[8][II], whh[8][HID], bias[8];
    #pragma unroll
    for (int gi = 0; gi < 4; ++gi) {
        #pragma unroll
        for (int s = 0; s < 2; ++s) {
            const int r = gi * 2 + s;
            const int row = gi * 8 + 2 * q + s;
            #pragma unroll
            for (int i = 0; i < II; ++i) wih[r][i] = W_ih[row * II + i];
            // pre-permute W_hh columns into XOR-partner order so the
            // per-step gather uses compile-time indices
            #pragma unroll
            for (int m = 0; m < HID; ++m) whh[r][m] = W_hh[row * HID + eidx[m]];
            bias[r] = b_ih[row] + b_hh[row];
        }
    }

    const float* xb = x + (size_t)b * (TT * II);
    float h0 = 0.f, h1 = 0.f, c0 = 0.f, c1 = 0.f, acc = 0.f;

    float xv[II];
    #pragma unroll
    for (int i = 0; i < II; ++i) xv[i] = xb[i];

    #pragma unroll 1
    for (int t = 0; t < TT; ++t) {
        // prefetch next timestep's x row (clamped at the end; stays in-bounds)
        float xn[II];
        const int tn = (t < TT - 1) ? t + 1 : t;
        #pragma unroll
        for (int i = 0; i < II; ++i) xn[i] = xb[tn * II + i];

        float g[8];
        #pragma unroll
        for (int r = 0; r < 8; ++r) g[r] = bias[r];
        #pragma unroll
        for (int i = 0; i < II; ++i) {
            #pragma unroll
            for (int r = 0; r < 8; ++r) g[r] = fmaf(wih[r][i], xv[i], g[r]);
        }

        // gather all 8 h values of this batch from the quad (pure-VALU DPP)
        float ha[8];
        ha[0] = h0;            ha[1] = h1;
        ha[2] = dppf<0xB1>(h0); ha[3] = dppf<0xB1>(h1);
        ha[4] = dppf<0x4E>(h0); ha[5] = dppf<0x4E>(h1);
        ha[6] = dppf<0x1B>(h0); ha[7] = dppf<0x1B>(h1);

        #pragma unroll
        for (int m = 0; m < HID; ++m) {
            #pragma unroll
            for (int r = 0; r < 8; ++r) g[r] = fmaf(whh[r][m], ha[m], g[r]);
        }

        const float i0 = fast_sigmoid(g[0]);
        const float i1 = fast_sigmoid(g[1]);
        const float f0 = fast_sigmoid(g[2]);
        const float f1 = fast_sigmoid(g[3]);
        const float t0 = fast_tanh(g[4]);
        const float t1 = fast_tanh(g[5]);
        const float o0 = fast_sigmoid(g[6]);
        const float o1 = fast_sigmoid(g[7]);
        c0 = fmaf(f0, c0, i0 * t0);
        c1 = fmaf(f1, c1, i1 * t1);
        h0 = o0 * fast_tanh(c0);
        h1 = o1 * fast_tanh(c1);

        const float2 fcv = *reinterpret_cast<const float2*>(&s_fc[t * HID + 2 * q]);
        acc = fmaf(h0, fcv.x, acc);
        acc = fmaf(h1, fcv.y, acc);

        #pragma unroll
        for (int i = 0; i < II; ++i) xv[i] = xn[i];
    }

    // reduce acc across the quad (sum of 8 h*w terms per t lives split over 4 lanes)
    acc += dppf<0xB1>(acc);
    acc += dppf<0x4E>(acc);
    if (q == 0) out[b] = acc + fc_b[0];
}

extern "C" void kernel_launch(void* const* d_in, const int* in_sizes, int n_in,
                              void* d_out, int out_size, void* d_ws, size_t ws_size,
                              hipStream_t stream) {
    const float* x    = (const float*)d_in[0];
    const float* W_ih = (const float*)d_in[1];
    const float* W_hh = (const float*)d_in[2];
    const float* b_ih = (const float*)d_in[3];
    const float* b_hh = (const float*)d_in[4];
    const float* fc_W = (const float*)d_in[5];
    const float* fc_b = (const float*)d_in[6];
    float* out = (float*)d_out;

    const int B = in_sizes[0] / (TT * II);
    const int batches_per_block = 64;  // 256 threads, 4 per batch
    const int grid = (B + batches_per_block - 1) / batches_per_block;
    lstm_fused<<<grid, 256, 0, stream>>>(x, W_ih, W_hh, b_ih, b_hh, fc_W, fc_b, out, B);
}

// Round 2
// 104.362 us; speedup vs baseline: 1.2058x; 1.2058x over previous
//
#include <hip/hip_runtime.h>

#define TT 48
#define II 5
#define HID 8

typedef float float2v __attribute__((ext_vector_type(2)));

// quad_perm DPP: value from lane (quad_base | perm[lane&3])
template<int CTRL>
__device__ __forceinline__ float dppf(float v) {
    return __int_as_float(__builtin_amdgcn_update_dpp(0, __float_as_int(v), CTRL, 0xF, 0xF, true));
}
// lane ^ 4 within each 32-lane half: BitMode offset = (4<<10) | 0x1F
__device__ __forceinline__ float swz4(float v) {
    return __int_as_float(__builtin_amdgcn_ds_swizzle(__float_as_int(v), 0x101F));
}
__device__ __forceinline__ float fexp2(float x) {
    float r;
    asm("v_exp_f32 %0, %1" : "=v"(r) : "v"(x));
    return r;
}
__device__ __forceinline__ float frcp(float x) { return __builtin_amdgcn_rcpf(x); }

__device__ __forceinline__ float2v pkfma(float2v a, float2v b, float2v c) {
    return __builtin_elementwise_fma(a, b, c);
}
__device__ __forceinline__ float2v splat(float v) { return (float2v){v, v}; }

__global__ __launch_bounds__(256, 4) void lstm_fused(
    const float* __restrict__ x,
    const float* __restrict__ W_ih,
    const float* __restrict__ W_hh,
    const float* __restrict__ b_ih,
    const float* __restrict__ b_hh,
    const float* __restrict__ fc_W,
    const float* __restrict__ fc_b,
    float* __restrict__ out, int B)
{
    __shared__ __align__(16) float s_fc[TT * HID];
    const int tid = threadIdx.x;
    for (int i = tid; i < TT * HID; i += 256) s_fc[i] = fc_W[i];
    __syncthreads();

    const int gt = blockIdx.x * 256 + tid;
    const int b = gt >> 3;       // 8 threads per batch element
    const int q = gt & 7;        // owned hidden unit
    if (b >= B) return;

    const float L2E  = 1.44269504088896340736f;
    const float L2E2 = 2.0f * L2E;

    // gate rows for hidden unit q (PyTorch order i,f,g,o)
    const int r_i = q, r_f = 8 + q, r_g = 16 + q, r_o = 24 + q;

    // pairs: A = (i,f) rows, B = (g,o) rows. Pre-scale by log2(e)
    // (2*log2(e) for the tanh-input g rows) so activations use raw exp2.
    float2v wihA[II], wihB[II], whhA[HID], whhB[HID], biasA, biasB;
    #pragma unroll
    for (int i = 0; i < II; ++i) {
        wihA[i] = (float2v){L2E  * W_ih[r_i * II + i], L2E * W_ih[r_f * II + i]};
        wihB[i] = (float2v){L2E2 * W_ih[r_g * II + i], L2E * W_ih[r_o * II + i]};
    }
    #pragma unroll
    for (int m = 0; m < HID; ++m) {
        const int e = q ^ m;  // column order matches xor-butterfly gather
        whhA[m] = (float2v){L2E  * W_hh[r_i * HID + e], L2E * W_hh[r_f * HID + e]};
        whhB[m] = (float2v){L2E2 * W_hh[r_g * HID + e], L2E * W_hh[r_o * HID + e]};
    }
    biasA = (float2v){L2E  * (b_ih[r_i] + b_hh[r_i]), L2E * (b_ih[r_f] + b_hh[r_f])};
    biasB = (float2v){L2E2 * (b_ih[r_g] + b_hh[r_g]), L2E * (b_ih[r_o] + b_hh[r_o])};

    const float* xb = x + (size_t)b * (TT * II);
    float h = 0.f, c = 0.f, acc = 0.f;

    float2v xv[II];
    #pragma unroll
    for (int i = 0; i < II; ++i) xv[i] = splat(xb[i]);

    #pragma unroll 4
    for (int t = 0; t < TT; ++t) {
        // prefetch next timestep's x row
        float xn[II];
        const int tn = (t < TT - 1) ? t + 1 : t;
        #pragma unroll
        for (int i = 0; i < II; ++i) xn[i] = xb[tn * II + i];

        // input projection (bias folded into first fma)
        float2v gA = pkfma(wihA[0], xv[0], biasA);
        float2v gB = pkfma(wihB[0], xv[0], biasB);
        #pragma unroll
        for (int i = 1; i < II; ++i) {
            gA = pkfma(wihA[i], xv[i], gA);
            gB = pkfma(wihB[i], xv[i], gB);
        }

        // gather all 8 h values of this batch: xor1/xor2 via DPP, xor4 via swizzle
        float ha0 = h;
        float ha1 = dppf<0xB1>(h);
        float ha2 = dppf<0x4E>(h);
        float ha3 = dppf<0x4E>(ha1);
        float ha4 = swz4(ha0), ha5 = swz4(ha1), ha6 = swz4(ha2), ha7 = swz4(ha3);

        gA = pkfma(whhA[0], splat(ha0), gA);  gB = pkfma(whhB[0], splat(ha0), gB);
        gA = pkfma(whhA[1], splat(ha1), gA);  gB = pkfma(whhB[1], splat(ha1), gB);
        gA = pkfma(whhA[2], splat(ha2), gA);  gB = pkfma(whhB[2], splat(ha2), gB);
        gA = pkfma(whhA[3], splat(ha3), gA);  gB = pkfma(whhB[3], splat(ha3), gB);
        gA = pkfma(whhA[4], splat(ha4), gA);  gB = pkfma(whhB[4], splat(ha4), gB);
        gA = pkfma(whhA[5], splat(ha5), gA);  gB = pkfma(whhB[5], splat(ha5), gB);
        gA = pkfma(whhA[6], splat(ha6), gA);  gB = pkfma(whhB[6], splat(ha6), gB);
        gA = pkfma(whhA[7], splat(ha7), gA);  gB = pkfma(whhB[7], splat(ha7), gB);

        // activations: inputs pre-scaled so sigma(x)=rcp(1+exp2(-s)),
        // tanh(x)=1-2*rcp(1+exp2(u)) with u=2*log2e*x
        const float si = frcp(1.0f + fexp2(-gA.x));
        const float sf = frcp(1.0f + fexp2(-gA.y));
        const float tg = fmaf(-2.0f, frcp(1.0f + fexp2(gB.x)), 1.0f);
        const float so = frcp(1.0f + fexp2(-gB.y));

        c = fmaf(sf, c, si * tg);
        const float tc = fmaf(-2.0f, frcp(1.0f + fexp2(c * L2E2)), 1.0f);
        h = so * tc;

        acc = fmaf(h, s_fc[t * HID + q], acc);

        #pragma unroll
        for (int i = 0; i < II; ++i) xv[i] = splat(xn[i]);
    }

    // reduce acc over the 8 lanes of this batch group
    acc += dppf<0xB1>(acc);
    acc += dppf<0x4E>(acc);
    acc += swz4(acc);
    if (q == 0) out[b] = acc + fc_b[0];
}

extern "C" void kernel_launch(void* const* d_in, const int* in_sizes, int n_in,
                              void* d_out, int out_size, void* d_ws, size_t ws_size,
                              hipStream_t stream) {
    const float* x    = (const float*)d_in[0];
    const float* W_ih = (const float*)d_in[1];
    const float* W_hh = (const float*)d_in[2];
    const float* b_ih = (const float*)d_in[3];
    const float* b_hh = (const float*)d_in[4];
    const float* fc_W = (const float*)d_in[5];
    const float* fc_b = (const float*)d_in[6];
    float* out = (float*)d_out;

    const int B = in_sizes[0] / (TT * II);
    const long long threads = (long long)B * 8;
    const int grid = (int)((threads + 255) / 256);
    lstm_fused<<<grid, 256, 0, stream>>>(x, W_ih, W_hh, b_ih, b_hh, fc_W, fc_b, out, B);
}